// Round 2
// baseline (2387.457 us; speedup 1.0000x reference)
//
#include <hip/hip_runtime.h>

#define TT 128
#define EE 768
#define NSEQ_TOTAL 920   // 200 support + 200 query + 512 unlabel + 8 model_ans

// ---------------------------------------------------------------------------
// fp32 tiled GEMM: C[M,N] = A[M,K] @ B[K,N] + bias[N]
// BM=BN=128, BK=16, 256 threads, 8x8 micro-tile per thread.
// M must be a multiple of 128, N a multiple of 128, K a multiple of 16.
// ---------------------------------------------------------------------------
__global__ __launch_bounds__(256, 2)
void gemm128(const float* __restrict__ A, int lda,
             const float* __restrict__ B, int ldb,
             const float* __restrict__ bias,
             float* __restrict__ C, int ldc, int K)
{
    __shared__ float As[16][128];   // [k][m]
    __shared__ float Bs[16][128];   // [k][n]

    const int m0 = blockIdx.x * 128;
    const int n0 = blockIdx.y * 128;
    const int t  = threadIdx.x;

    const int la_m = t >> 2;          // 0..63 (row, plus +64 for second)
    const int la_k = (t & 3) << 2;    // 0,4,8,12
    const int lb_k = t >> 5;          // 0..7 (plus +8)
    const int lb_n = (t & 31) << 2;   // 0..124
    const int tx = t & 15;            // row group: 8 rows
    const int ty = t >> 4;            // col group: 8 cols

    float acc[8][8];
#pragma unroll
    for (int i = 0; i < 8; ++i)
#pragma unroll
        for (int j = 0; j < 8; ++j) acc[i][j] = 0.f;

    for (int k0 = 0; k0 < K; k0 += 16) {
        float4 a0 = *(const float4*)&A[(size_t)(m0 + la_m)      * lda + k0 + la_k];
        float4 a1 = *(const float4*)&A[(size_t)(m0 + la_m + 64) * lda + k0 + la_k];
        float4 b0 = *(const float4*)&B[(size_t)(k0 + lb_k)     * ldb + n0 + lb_n];
        float4 b1 = *(const float4*)&B[(size_t)(k0 + lb_k + 8) * ldb + n0 + lb_n];

        __syncthreads();   // previous compute done reading LDS
        As[la_k + 0][la_m] = a0.x; As[la_k + 1][la_m] = a0.y;
        As[la_k + 2][la_m] = a0.z; As[la_k + 3][la_m] = a0.w;
        As[la_k + 0][la_m + 64] = a1.x; As[la_k + 1][la_m + 64] = a1.y;
        As[la_k + 2][la_m + 64] = a1.z; As[la_k + 3][la_m + 64] = a1.w;
        *(float4*)&Bs[lb_k][lb_n]     = b0;
        *(float4*)&Bs[lb_k + 8][lb_n] = b1;
        __syncthreads();

#pragma unroll
        for (int kk = 0; kk < 16; ++kk) {
            float4 av0 = *(const float4*)&As[kk][tx * 8];
            float4 av1 = *(const float4*)&As[kk][tx * 8 + 4];
            float4 bv0 = *(const float4*)&Bs[kk][ty * 8];
            float4 bv1 = *(const float4*)&Bs[kk][ty * 8 + 4];
            float am[8] = {av0.x, av0.y, av0.z, av0.w, av1.x, av1.y, av1.z, av1.w};
            float bn[8] = {bv0.x, bv0.y, bv0.z, bv0.w, bv1.x, bv1.y, bv1.z, bv1.w};
#pragma unroll
            for (int i = 0; i < 8; ++i)
#pragma unroll
                for (int j = 0; j < 8; ++j)
                    acc[i][j] = fmaf(am[i], bn[j], acc[i][j]);
        }
    }

    float bb[8];
#pragma unroll
    for (int j = 0; j < 8; ++j) bb[j] = bias[n0 + ty * 8 + j];

#pragma unroll
    for (int i = 0; i < 8; ++i) {
        float* cp = &C[(size_t)(m0 + tx * 8 + i) * ldc + n0 + ty * 8];
        float4 o0, o1;
        o0.x = acc[i][0] + bb[0]; o0.y = acc[i][1] + bb[1];
        o0.z = acc[i][2] + bb[2]; o0.w = acc[i][3] + bb[3];
        o1.x = acc[i][4] + bb[4]; o1.y = acc[i][5] + bb[5];
        o1.z = acc[i][6] + bb[6]; o1.w = acc[i][7] + bb[7];
        *(float4*)cp       = o0;
        *(float4*)(cp + 4) = o1;
    }
}

__device__ __forceinline__ float sigf(float x) { return 1.f / (1.f + expf(-x)); }

// ---------------------------------------------------------------------------
// LSTM layer 1 recurrence. One block (512 threads) per sequence.
// Thread c owns output column c of z = h @ U + xw_t  (4H = 512, H = 128).
// U column held in registers; h broadcast via LDS. Keras gate order i,f,g,o.
// Writes the full h-sequence [TT,128] per sequence (return_sequences=True).
// ---------------------------------------------------------------------------
__global__ __launch_bounds__(512, 2)
void lstm1_rec(const float* __restrict__ xw, const float* __restrict__ U,
               float* __restrict__ hseq)
{
    const int c = threadIdx.x;              // 0..511
    const size_t blk = blockIdx.x;
    const float* xwp = xw + blk * (size_t)(TT * 512);
    float* hout = hseq + blk * (size_t)(TT * 128);

    float u[128];
#pragma unroll
    for (int j = 0; j < 128; ++j) u[j] = U[j * 512 + c];

    __shared__ __align__(16) float h_sh[128];
    __shared__ float z_sh[512];
    float cstate = 0.f;
    if (c < 128) h_sh[c] = 0.f;
    float xw_t = xwp[c];
    __syncthreads();

    for (int t = 0; t < TT; ++t) {
        float acc = xw_t;
        const float4* h4 = (const float4*)h_sh;
#pragma unroll
        for (int j = 0; j < 32; ++j) {
            float4 hv = h4[j];
            acc = fmaf(u[4 * j + 0], hv.x, acc);
            acc = fmaf(u[4 * j + 1], hv.y, acc);
            acc = fmaf(u[4 * j + 2], hv.z, acc);
            acc = fmaf(u[4 * j + 3], hv.w, acc);
        }
        if (t + 1 < TT) xw_t = xwp[(size_t)(t + 1) * 512 + c];
        z_sh[c] = acc;
        __syncthreads();
        if (c < 128) {
            float zi = z_sh[c];
            float zf = z_sh[c + 128];
            float zg = z_sh[c + 256];
            float zo = z_sh[c + 384];
            cstate = sigf(zf) * cstate + sigf(zi) * tanhf(zg);
            float h = sigf(zo) * tanhf(cstate);
            h_sh[c] = h;
            hout[t * 128 + c] = h;
        }
        __syncthreads();
    }
}

// ---------------------------------------------------------------------------
// LSTM layer 2 recurrence. One block (256 threads) per sequence. H = 64.
// Only final h is kept (return_sequences=False) -> enc[seq, 64].
// ---------------------------------------------------------------------------
__global__ __launch_bounds__(256, 2)
void lstm2_rec(const float* __restrict__ xw, const float* __restrict__ U,
               float* __restrict__ enc, int seq0)
{
    const int c = threadIdx.x;              // 0..255
    const size_t blk = blockIdx.x;
    const float* xwp = xw + blk * (size_t)(TT * 256);

    float u[64];
#pragma unroll
    for (int j = 0; j < 64; ++j) u[j] = U[j * 256 + c];

    __shared__ __align__(16) float h_sh[64];
    __shared__ float z_sh[256];
    float cstate = 0.f;
    if (c < 64) h_sh[c] = 0.f;
    float xw_t = xwp[c];
    __syncthreads();

    for (int t = 0; t < TT; ++t) {
        float acc = xw_t;
        const float4* h4 = (const float4*)h_sh;
#pragma unroll
        for (int j = 0; j < 16; ++j) {
            float4 hv = h4[j];
            acc = fmaf(u[4 * j + 0], hv.x, acc);
            acc = fmaf(u[4 * j + 1], hv.y, acc);
            acc = fmaf(u[4 * j + 2], hv.z, acc);
            acc = fmaf(u[4 * j + 3], hv.w, acc);
        }
        if (t + 1 < TT) xw_t = xwp[(size_t)(t + 1) * 256 + c];
        z_sh[c] = acc;
        __syncthreads();
        if (c < 64) {
            float zi = z_sh[c];
            float zf = z_sh[c + 64];
            float zg = z_sh[c + 128];
            float zo = z_sh[c + 192];
            cstate = sigf(zf) * cstate + sigf(zi) * tanhf(zg);
            float h = sigf(zo) * tanhf(cstate);
            h_sh[c] = h;
            if (t == TT - 1) enc[(size_t)(seq0 + (int)blk) * 64 + c] = h;
        }
        __syncthreads();
    }
}

// ---------------------------------------------------------------------------
// Heads: out_row = BN(relu(concat(enc[er], enc[mr]) @ W + b))
// d_s rows 0..199 (head1), d_q rows 200..399 (head2), d_u rows 400..911 (head3)
// ---------------------------------------------------------------------------
__global__ void heads_kernel(const float* __restrict__ enc,
    const float* W1, const float* B1, const float* G1, const float* Be1, const float* M1, const float* V1,
    const float* W2, const float* B2, const float* G2, const float* Be2, const float* M2, const float* V2,
    const float* W3, const float* B3, const float* G3, const float* Be3, const float* M3, const float* V3,
    float* __restrict__ out)
{
    int e = blockIdx.x * 256 + threadIdx.x;
    if (e >= 912 * 32) return;
    int row = e >> 5, d = e & 31;

    const float *W, *B, *G, *Bt, *Mn, *Vr;
    int er, mr;
    if (row < 200) {
        W = W1; B = B1; G = G1; Bt = Be1; Mn = M1; Vr = V1;
        er = row;            mr = 912 + row / 25;          // nc*ss = 25
    } else if (row < 400) {
        int r = row - 200;
        W = W2; B = B2; G = G2; Bt = Be2; Mn = M2; Vr = V2;
        er = 200 + r;        mr = 912 + r / 25;            // nc*qs = 25
    } else {
        int r = row - 400;
        W = W3; B = B3; G = G3; Bt = Be3; Mn = M3; Vr = V3;
        er = 400 + r;        mr = 912 + r / 64;            // nu*nseq = 64
    }

    const float* xa = enc + (size_t)er * 64;
    const float* xb = enc + (size_t)mr * 64;
    float s = B[d];
#pragma unroll 4
    for (int k = 0; k < 64; ++k) s = fmaf(xa[k], W[k * 32 + d], s);
#pragma unroll 4
    for (int k = 0; k < 64; ++k) s = fmaf(xb[k], W[(64 + k) * 32 + d], s);
    s = fmaxf(s, 0.f);
    s = G[d] * (s - Mn[d]) * rsqrtf(Vr[d] + 1e-3f) + Bt[d];
    out[e] = s;
}

// ---------------------------------------------------------------------------
extern "C" void kernel_launch(void* const* d_in, const int* in_sizes, int n_in,
                              void* d_out, int out_size, void* d_ws, size_t ws_size,
                              hipStream_t stream)
{
    const float* sup  = (const float*)d_in[0];
    const float* qry  = (const float*)d_in[1];
    const float* unl  = (const float*)d_in[2];
    const float* mans = (const float*)d_in[3];
    const float* W1   = (const float*)d_in[4];
    const float* U1   = (const float*)d_in[5];
    const float* b1   = (const float*)d_in[6];
    const float* W2   = (const float*)d_in[7];
    const float* U2   = (const float*)d_in[8];
    const float* b2   = (const float*)d_in[9];

    // workspace layout: enc[920*64] | xw1 (chunk, also reused as xw2) | h1seq (chunk)
    float* enc = (float*)d_ws;
    size_t enc_bytes = (size_t)NSEQ_TOTAL * 64 * sizeof(float);
    size_t off = (enc_bytes + 255) & ~(size_t)255;
    size_t per_seq = (size_t)TT * 512 * sizeof(float)   // xw1 row block
                   + (size_t)TT * 128 * sizeof(float);  // h1seq row block
    int C = NSEQ_TOTAL;
    if (off + (size_t)NSEQ_TOTAL * per_seq > ws_size) {
        C = (int)((ws_size > off ? ws_size - off : 0) / per_seq);
        if (C < 1) C = 1;
        if (C > NSEQ_TOTAL) C = NSEQ_TOTAL;
    }
    float* xw1 = (float*)((char*)d_ws + off);
    float* h1  = (float*)((char*)d_ws + off + (size_t)C * TT * 512 * sizeof(float));

    struct Rng { const float* base; int s0, s1; };
    Rng rngs[4] = { {sup, 0, 200}, {qry, 200, 400}, {unl, 400, 912}, {mans, 912, 920} };

    for (int s0 = 0; s0 < NSEQ_TOTAL; s0 += C) {
        int ns = (NSEQ_TOTAL - s0 < C) ? (NSEQ_TOTAL - s0) : C;

        // phase 1: xw1 = X @ W1 + b1   (per overlapping input tensor)
        for (int r = 0; r < 4; ++r) {
            int lo = rngs[r].s0 > s0 ? rngs[r].s0 : s0;
            int hi = rngs[r].s1 < s0 + ns ? rngs[r].s1 : s0 + ns;
            if (lo >= hi) continue;
            const float* A = rngs[r].base + (size_t)(lo - rngs[r].s0) * TT * EE;
            float* o = xw1 + (size_t)(lo - s0) * TT * 512;
            gemm128<<<dim3(hi - lo, 4), 256, 0, stream>>>(A, EE, W1, 512, b1, o, 512, EE);
        }
        // phase 2: LSTM1 recurrence -> h1 sequence
        lstm1_rec<<<ns, 512, 0, stream>>>(xw1, U1, h1);
        // phase 3: xw2 = h1 @ W2 + b2 (writes into xw1 buffer, no longer needed)
        gemm128<<<dim3(ns, 2), 256, 0, stream>>>(h1, 128, W2, 256, b2, xw1, 256, 128);
        // phase 4: LSTM2 recurrence -> enc
        lstm2_rec<<<ns, 256, 0, stream>>>(xw1, U2, enc, s0);
    }

    heads_kernel<<<(912 * 32 + 255) / 256, 256, 0, stream>>>(enc,
        (const float*)d_in[10], (const float*)d_in[11], (const float*)d_in[12],
        (const float*)d_in[13], (const float*)d_in[14], (const float*)d_in[15],
        (const float*)d_in[16], (const float*)d_in[17], (const float*)d_in[18],
        (const float*)d_in[19], (const float*)d_in[20], (const float*)d_in[21],
        (const float*)d_in[22], (const float*)d_in[23], (const float*)d_in[24],
        (const float*)d_in[25], (const float*)d_in[26], (const float*)d_in[27],
        (float*)d_out);
}